// Round 7
// baseline (411.216 us; speedup 1.0000x reference)
//
#include <hip/hip_runtime.h>
#include <cstdint>
#include <cstddef>

typedef unsigned short u16;
typedef short short8 __attribute__((ext_vector_type(8)));
typedef float f32x4 __attribute__((ext_vector_type(4)));

#define B_   2
#define T_   2048
#define H_   16
#define HID_ 2048
#define DQK_ 192
#define DV_  128
#define AW_  3072   // fused a-proj output width (q_a 1536 | kv_raw 1536)

__device__ __forceinline__ float bf2f(u16 u) {
  unsigned int v = ((unsigned int)u) << 16;
  return __builtin_bit_cast(float, v);
}
__device__ __forceinline__ u16 f2bf(float f) {
  unsigned int u = __builtin_bit_cast(unsigned int, f);
  u += 0x7fff + ((u >> 16) & 1);   // round-to-nearest-even
  return (u16)(u >> 16);
}
__device__ __forceinline__ void load_lds16(const void* g, void* l) {
  __builtin_amdgcn_global_load_lds((const __attribute__((address_space(1))) void*)g,
                                   (__attribute__((address_space(3))) void*)l, 16, 0, 0);
}

// ---------------- cast f32 -> bf16 (8 elems/thread) ----------------
__global__ __launch_bounds__(256) void cast_f32_bf16(const float* __restrict__ x,
                                                     u16* __restrict__ y) {
  size_t i = ((size_t)blockIdx.x * 256 + threadIdx.x) * 8;
  float4 a = *(const float4*)&x[i];
  float4 b = *(const float4*)&x[i + 4];
  u16 r[8];
  r[0] = f2bf(a.x); r[1] = f2bf(a.y); r[2] = f2bf(a.z); r[3] = f2bf(a.w);
  r[4] = f2bf(b.x); r[5] = f2bf(b.y); r[6] = f2bf(b.z); r[7] = f2bf(b.w);
  *(uint4*)&y[i] = *(const uint4*)&r[0];
}

// ---------------- W (K x N) f32  ->  Wt (N x K) bf16 ----------------
__global__ __launch_bounds__(256) void transpose_cast_k(const float* __restrict__ W,
                                                        u16* __restrict__ Wt,
                                                        int K, int N) {
  __shared__ u16 tile[32][33];
  int n0 = blockIdx.x * 32, k0 = blockIdx.y * 32;
  int tx = threadIdx.x & 31, ty = threadIdx.x >> 5;
#pragma unroll
  for (int i = 0; i < 32; i += 8)
    tile[ty + i][tx] = f2bf(W[(size_t)(k0 + ty + i) * N + n0 + tx]);
  __syncthreads();
#pragma unroll
  for (int i = 0; i < 32; i += 8)
    Wt[(size_t)(n0 + ty + i) * K + k0 + tx] = tile[tx][ty + i];
}

// ---------------- RMSNorm over rows (bf16 in/out, f32 weight) ----------------
__global__ __launch_bounds__(256) void rmsnorm_k(const u16* __restrict__ in, int in_stride,
                                                 int L, const float* __restrict__ w,
                                                 u16* __restrict__ out, int out_stride) {
  int row = blockIdx.x;
  const u16* x = in + (size_t)row * in_stride;
  float ss = 0.f;
  for (int i = threadIdx.x * 8; i < L; i += 2048) {
    uint4 v = *(const uint4*)&x[i];
    const u16* p = (const u16*)&v;
#pragma unroll
    for (int e = 0; e < 8; ++e) { float f = bf2f(p[e]); ss += f * f; }
  }
#pragma unroll
  for (int m = 32; m >= 1; m >>= 1) ss += __shfl_xor(ss, m);
  __shared__ float red[4];
  if ((threadIdx.x & 63) == 0) red[threadIdx.x >> 6] = ss;
  __syncthreads();
  ss = red[0] + red[1] + red[2] + red[3];
  float inv = rsqrtf(ss / (float)L + 1e-6f);
  u16* o = out + (size_t)row * out_stride;
  for (int i = threadIdx.x * 8; i < L; i += 2048) {
    uint4 v = *(const uint4*)&x[i];
    const u16* p = (const u16*)&v;
    u16 r8[8];
#pragma unroll
    for (int e = 0; e < 8; ++e) r8[e] = f2bf(bf2f(p[e]) * inv * w[i + e]);
    *(uint4*)&o[i] = *(const uint4*)&r8[0];
  }
}

// ---------------- GEMM: A(MxK) bf16 row-major, Bt(NxK) bf16, C(MxN) ----------------
// m97 structure: 128x128 tile, BK=32, 4 waves (2x2), each 64x64 (4x4 16x16 frags)
// EPI: 0 = f32 row-major, 1 = bf16 row-major, 3 = bf16 row-major * softmax scale
template <int EPI>
__global__ __launch_bounds__(256) void gemm_bt(const u16* __restrict__ A,
                                               const u16* __restrict__ Bt,
                                               void* __restrict__ Cout,
                                               int M, int N, int K) {
  __shared__ u16 As[128 * 32];
  __shared__ u16 Bs[128 * 32];
  const int nbx = N >> 7;
  const int bx = blockIdx.x % nbx, by = blockIdx.x / nbx;
  const int m0 = by << 7, n0 = bx << 7;
  const int tid = threadIdx.x, w = tid >> 6, lane = tid & 63;
  const int wr = w >> 1, wc = w & 1;
  const int llo = lane & 15, lhi = lane >> 4;
  f32x4 acc[4][4] = {};
  const u16* Ag = A + (size_t)(m0 + w * 32 + (lane >> 2)) * K + (lane & 3) * 8;
  const u16* Bg = Bt + (size_t)(n0 + w * 32 + (lane >> 2)) * K + (lane & 3) * 8;
  u16* Al = &As[(w * 32 + (lane >> 2)) * 32 + (lane & 3) * 8];
  u16* Bl = &Bs[(w * 32 + (lane >> 2)) * 32 + (lane & 3) * 8];
  for (int k0 = 0; k0 < K; k0 += 32) {
    load_lds16(Ag + k0, Al);
    load_lds16(Ag + k0 + (size_t)16 * K, Al + 16 * 32);
    load_lds16(Bg + k0, Bl);
    load_lds16(Bg + k0 + (size_t)16 * K, Bl + 16 * 32);
    __syncthreads();
    short8 af[4], bfr[4];
#pragma unroll
    for (int i = 0; i < 4; ++i)
      af[i] = *(const short8*)&As[(wr * 64 + i * 16 + llo) * 32 + lhi * 8];
#pragma unroll
    for (int j = 0; j < 4; ++j)
      bfr[j] = *(const short8*)&Bs[(wc * 64 + j * 16 + llo) * 32 + lhi * 8];
#pragma unroll
    for (int i = 0; i < 4; ++i)
#pragma unroll
      for (int j = 0; j < 4; ++j)
        acc[i][j] = __builtin_amdgcn_mfma_f32_16x16x32_bf16(af[i], bfr[j], acc[i][j], 0, 0, 0);
    __syncthreads();
  }
  if constexpr (EPI == 0) {
    float* C = (float*)Cout;
#pragma unroll
    for (int i = 0; i < 4; ++i)
#pragma unroll
      for (int j = 0; j < 4; ++j)
#pragma unroll
        for (int r = 0; r < 4; ++r)
          C[(size_t)(m0 + wr * 64 + i * 16 + lhi * 4 + r) * N + (n0 + wc * 64 + j * 16 + llo)] =
              acc[i][j][r];
  } else {
    const float scale = (EPI == 3) ? 0.10412163f : 1.0f;  // log2(e)/sqrt(192)
    u16* C = (u16*)Cout;
#pragma unroll
    for (int i = 0; i < 4; ++i)
#pragma unroll
      for (int j = 0; j < 4; ++j)
#pragma unroll
        for (int r = 0; r < 4; ++r)
          C[(size_t)(m0 + wr * 64 + i * 16 + lhi * 4 + r) * N + (n0 + wc * 64 + j * 16 + llo)] =
              f2bf(acc[i][j][r] * scale);
  }
}

// ---------------- V repack: kv cols 128..255 per head -> Vt (B,H,128,T) ----------------
__global__ __launch_bounds__(256) void pack_vt_k(const u16* __restrict__ kv, u16* __restrict__ Vt) {
  __shared__ u16 tile[64][136];
  const int nt = T_ / 64;  // 32
  int t0 = (blockIdx.x % nt) * 64;
  int bh = blockIdx.x / nt;
  int b = bh >> 4, h = bh & 15;
  int row = threadIdx.x >> 4;     // 0..15
  int ck = threadIdx.x & 15;      // 16 chunks of 8 = 128 dims
#pragma unroll
  for (int i = 0; i < 64; i += 16) {
    uint4 v = *(const uint4*)&kv[((size_t)(b * T_) + t0 + row + i) * 4096 + h * 256 + 128 + ck * 8];
    *(uint4*)&tile[row + i][ck * 8] = v;
  }
  __syncthreads();
  int d = threadIdx.x >> 1;
  int th = (threadIdx.x & 1) * 32;
  u16 tmp[32];
#pragma unroll
  for (int e = 0; e < 32; ++e) tmp[e] = tile[th + e][d];
#pragma unroll
  for (int e = 0; e < 32; e += 8)
    *(uint4*)&Vt[((size_t)bh * 128 + d) * T_ + t0 + th + e] = *(const uint4*)&tmp[e];
}

// ---------------- causal flash attention: 512-thr shared-staging blocks ----------------
// 8 waves: waves 0-3 -> q-tile qtL=31-pr, waves 4-7 -> q-tile qtS=pr, SHARING one
// K/V staging stream (staged bytes/FLOP halved vs r6). Short-group waves idle at
// barriers past their causal range (wave-uniform guard). LDS = 48K(K dbuf)+16K(V)
// +16K(P) = 80 KB -> exactly 2 blocks/CU = 16 waves/CU (2x r6 occupancy).
// Block mapping: raw&7 = XCD (4 bh per XCD, both layers -> K/V L2-resident);
// layer 0 (raw<256) runs pr 0..7, layer 1 runs pr 15..8 so co-resident blocks
// sum to uniform 49 k-tiles (balance under round-robin dispatch).
// Staging/swizzle/softmax math identical to r6 (verified): counted vmcnt
// (V=2 loads, K=3 loads -> vmcnt(3)), source-side XOR swizzle (rule #21),
// exp2 softmax w/ prefolded scale, defer-max THR=8, deferred l-reduce.
__global__ __launch_bounds__(512, 4) void attn_k(const u16* __restrict__ q,
                                                 const u16* __restrict__ kv,
                                                 const u16* __restrict__ kvraw,
                                                 const u16* __restrict__ Vt,
                                                 u16* __restrict__ att) {
  constexpr int KLD = 192, VLD = 64, PLD = 64;
  __shared__ u16 Ks[2][64 * KLD];   // 48 KB
  __shared__ u16 Vs[128 * VLD];     // 16 KB
  __shared__ u16 Ps[128 * PLD];     // 16 KB
  const int raw = (int)blockIdx.x;
  const int lay = raw >> 8;                    // 0 or 1 (co-resident layers)
  const int base = raw & 255;
  const int xcd = base & 7, sub = base >> 3;   // sub 0..31
  const int bh = xcd * 4 + (sub >> 3);         // 4 bh per XCD
  const int prr = sub & 7;
  const int pr = lay ? (15 - prr) : prr;       // layer pairs: (32-p)+(17+p)=49 tiles
  const int qtL = 31 - pr, qtS = pr;
  const int b = bh >> 4, h = bh & 15;
  const int bT = b * T_;
  const int tid = threadIdx.x, w = tid >> 6, lane = tid & 63;
  const int llo = lane & 15, lhi = lane >> 4;
  const int qt_w = (w < 4) ? qtL : qtS;        // this wave's q-tile
  const int rbase = qt_w * 64 + (w & 3) * 16;  // wave's first q-row
  const u16* Vb = Vt + (size_t)bh * DV_ * T_;

  // per-thread K staging sources (3 chunks/thread), swizzle folded into source
  const u16* kbase[3]; int kstr[3];
#pragma unroll
  for (int ii = 0; ii < 3; ++ii) {
    int c = ii * 512 + tid;            // 1536 chunks = 64 rows x 24 chunks
    int rr = c / 24, chk = c - rr * 24;
    int sc = chk ^ (rr & 7);           // source chunk for linear LDS slot
    if (sc < 16) { kbase[ii] = kv + (size_t)(bT + rr) * 4096 + h * 256 + sc * 8; kstr[ii] = 4096; }
    else { kbase[ii] = kvraw + (size_t)(bT + rr) * AW_ + 2048 + h * 64 + (sc - 16) * 8; kstr[ii] = AW_; }
  }
  int voff[2];
#pragma unroll
  for (int ii = 0; ii < 2; ++ii) {
    int c = ii * 512 + tid;            // 1024 chunks = 128 d-rows x 8 chunks
    int rr = c >> 3, chk = c & 7;
    voff[ii] = rr * T_ + (chk ^ (rr & 7)) * 8;
  }

  // Q frags for this wave's 16 q-rows
  short8 qf[6];
#pragma unroll
  for (int kk = 0; kk < 6; ++kk)
    qf[kk] = *(const short8*)&q[(size_t)(bT + rbase + llo) * AW_ + h * DQK_ + kk * 32 + lhi * 8];
  f32x4 oacc[8] = {};
  float m_r[4], l_r[4];
#pragma unroll
  for (int r = 0; r < 4; ++r) { m_r[r] = -1e30f; l_r[r] = 0.f; }

  // prologue: stage K[0]
#pragma unroll
  for (int ii = 0; ii < 3; ++ii)
    load_lds16(kbase[ii], &Ks[0][(ii * 512 + tid) * 8]);
  asm volatile("s_waitcnt vmcnt(0)" ::: "memory");
  __builtin_amdgcn_s_barrier();
  __builtin_amdgcn_sched_barrier(0);

  const int nktL = qtL + 1;
  int cur = 0;
  for (int kt = 0; kt < nktL; ++kt) {
    const int k0 = kt * 64;
    const bool hasNext = (kt + 1 < nktL);
    const bool active = (kt <= qt_w);    // wave-uniform
    // issue V[kt] -> Vs (2 loads)
#pragma unroll
    for (int ii = 0; ii < 2; ++ii)
      load_lds16(Vb + k0 + voff[ii], &Vs[(ii * 512 + tid) * 8]);
    // issue K[kt+1] -> other buffer (3 loads)
    if (hasNext) {
      u16* kd = Ks[cur ^ 1];
#pragma unroll
      for (int ii = 0; ii < 3; ++ii)
        load_lds16(kbase[ii] + (size_t)(k0 + 64) * kstr[ii], &kd[(ii * 512 + tid) * 8]);
    }
    if (active) {
      // S = Q K^T from Ks[cur]
      const u16* kbuf = Ks[cur];
      f32x4 s[4] = {};
      __builtin_amdgcn_s_setprio(1);
#pragma unroll
      for (int kk = 0; kk < 6; ++kk) {
        const int col = kk * 32 + lhi * 8;
        short8 kf[4];
#pragma unroll
        for (int j = 0; j < 4; ++j) {
          const int row = j * 16 + llo;
          kf[j] = *(const short8*)&kbuf[row * KLD + (col ^ ((row & 7) << 3))];
        }
#pragma unroll
        for (int j = 0; j < 4; ++j)
          s[j] = __builtin_amdgcn_mfma_f32_16x16x32_bf16(qf[kk], kf[j], s[j], 0, 0, 0);
      }
      __builtin_amdgcn_s_setprio(0);
      // online softmax (exp2 domain; Q pre-scaled by log2e/sqrt(192))
      const bool needMask = (k0 + 63 > rbase);
#pragma unroll
      for (int r = 0; r < 4; ++r) {
        const int qrow = rbase + lhi * 4 + r;
        float sv[4];
#pragma unroll
        for (int j = 0; j < 4; ++j) {
          float x = s[j][r];
          if (needMask) { int kcol = k0 + j * 16 + llo; x = (kcol <= qrow) ? x : -1e30f; }
          sv[j] = x;
        }
        float mx = fmaxf(fmaxf(sv[0], sv[1]), fmaxf(sv[2], sv[3]));
#pragma unroll
        for (int mk = 1; mk < 16; mk <<= 1) mx = fmaxf(mx, __shfl_xor(mx, mk));
        if (!__all(mx - m_r[r] <= 8.f)) {   // defer-max (T13)
          float mnew = fmaxf(m_r[r], mx);
          float alpha = exp2f(m_r[r] - mnew);
          m_r[r] = mnew;
          l_r[r] *= alpha;
#pragma unroll
          for (int jo = 0; jo < 8; ++jo) oacc[jo][r] *= alpha;
        }
        float rs = 0.f;
        const int prow = w * 16 + lhi * 4 + r;
#pragma unroll
        for (int j = 0; j < 4; ++j) {
          float p = exp2f(sv[j] - m_r[r]);
          rs += p;
          int pcol = j * 16 + llo;
          Ps[prow * PLD + (pcol ^ ((prow & 7) << 3))] = f2bf(p);
        }
        l_r[r] += rs;   // per-lane partial; cross-lane reduce in epilogue
      }
    }
    // V staged? (counted: leave the 3 K loads in flight)
    if (hasNext) asm volatile("s_waitcnt vmcnt(3)" ::: "memory");
    else         asm volatile("s_waitcnt vmcnt(0)" ::: "memory");
    __builtin_amdgcn_s_barrier();
    __builtin_amdgcn_sched_barrier(0);
    if (active) {
      // PV (wave-local P rows; same-wave LDS RAW ordered by lgkmcnt)
      __builtin_amdgcn_s_setprio(1);
#pragma unroll
      for (int kk2 = 0; kk2 < 2; ++kk2) {
        const int prow = w * 16 + llo;
        const int pcol = kk2 * 32 + lhi * 8;
        short8 pf = *(const short8*)&Ps[prow * PLD + (pcol ^ ((prow & 7) << 3))];
#pragma unroll
        for (int jo = 0; jo < 8; ++jo) {
          const int vrow = jo * 16 + llo;
          short8 vf = *(const short8*)&Vs[vrow * VLD + (pcol ^ ((vrow & 7) << 3))];
          oacc[jo] = __builtin_amdgcn_mfma_f32_16x16x32_bf16(pf, vf, oacc[jo], 0, 0, 0);
        }
      }
      __builtin_amdgcn_s_setprio(0);
    }
    // end of tile: K[t+1] landed; all waves done with Vs & Ks[cur]
    asm volatile("s_waitcnt vmcnt(0)" ::: "memory");
    __builtin_amdgcn_s_barrier();
    __builtin_amdgcn_sched_barrier(0);
    cur ^= 1;
  }
  // epilogue: reduce l partials across 16-lane group, store
#pragma unroll
  for (int r = 0; r < 4; ++r) {
    float lr = l_r[r];
#pragma unroll
    for (int mk = 1; mk < 16; mk <<= 1) lr += __shfl_xor(lr, mk);
    const int qrow = rbase + lhi * 4 + r;
    const float linv = 1.f / lr;
#pragma unroll
    for (int jo = 0; jo < 8; ++jo)
      att[((size_t)bT + qrow) * (H_ * DV_) + h * DV_ + jo * 16 + llo] =
          f2bf(oacc[jo][r] * linv);
  }
}

// ---------------- launch ----------------
extern "C" void kernel_launch(void* const* d_in, const int* in_sizes, int n_in,
                              void* d_out, int out_size, void* d_ws, size_t ws_size,
                              hipStream_t stream) {
  const float* hs      = (const float*)d_in[0];
  const float* q_a_w   = (const float*)d_in[1];
  const float* q_a_ln  = (const float*)d_in[2];
  const float* q_b_w   = (const float*)d_in[3];
  const float* kv_a_w  = (const float*)d_in[4];
  const float* kv_a_ln = (const float*)d_in[5];
  const float* kv_b_w  = (const float*)d_in[6];
  const float* o_w     = (const float*)d_in[7];
  float* out = (float*)d_out;
  char* ws = (char*)d_ws;

  u16* hid  = (u16*)(ws + 0);          // 16.78 MB  (B*T, 2048) bf16
  u16* wt   = (u16*)(ws + 16777216);   // 12.58 MB  transposed weight (reused)
  u16* qa   = (u16*)(ws + 29360128);   // 25.17 MB  fused a-out: [q_a 1536 | kv_raw 1536]
  u16* qan  = (u16*)(ws + 54525952);   // 12.58 MB  q_a normed / later kv_latent
  u16* qout = (u16*)(ws + 67108864);   // 25.17 MB  q (B*T, 16*192), pre-scaled
  u16* att  = (u16*)(ws + 92274688);   // 16.78 MB  attn out (B*T, 2048)
  u16* kv   = (u16*)(ws + 109051904);  // 33.55 MB  kv_b out (k_nope|v per head)
  u16* Vt   = (u16*)(ws + 142606336);  // 16.78 MB  (B,H,128,T)

  cast_f32_bf16<<<4096, 256, 0, stream>>>(hs, hid);

  // fused a-proj: [q_a | kv_raw] = hid @ [q_a_w | kv_a_w]
  transpose_cast_k<<<dim3(1536 / 32, 2048 / 32), 256, 0, stream>>>(q_a_w, wt, 2048, 1536);
  transpose_cast_k<<<dim3(1536 / 32, 2048 / 32), 256, 0, stream>>>(kv_a_w, wt + (size_t)1536 * 2048, 2048, 1536);
  gemm_bt<1><<<(3072 / 128) * (4096 / 128), 256, 0, stream>>>(hid, wt, qa, 4096, 3072, 2048);

  // rmsnorm q_a -> qan
  rmsnorm_k<<<4096, 256, 0, stream>>>(qa, AW_, 1536, q_a_ln, qan, 1536);

  // q = qan @ q_b_w  (bf16, pre-scaled by log2e/sqrt(192))
  transpose_cast_k<<<dim3(3072 / 32, 1536 / 32), 256, 0, stream>>>(q_b_w, wt, 1536, 3072);
  gemm_bt<3><<<(3072 / 128) * (4096 / 128), 256, 0, stream>>>(qan, wt, qout, 4096, 3072, 1536);

  // rmsnorm kv latent (kv_raw = qa cols 1536..2047) -> qan (stride 512)
  rmsnorm_k<<<4096, 256, 0, stream>>>(qa + 1536, AW_, 512, kv_a_ln, qan, 512);

  // kv = kv_latent @ kv_b_w
  transpose_cast_k<<<dim3(4096 / 32, 512 / 32), 256, 0, stream>>>(kv_b_w, wt, 512, 4096);
  gemm_bt<1><<<(4096 / 128) * (4096 / 128), 256, 0, stream>>>(qan, wt, kv, 4096, 4096, 512);

  // V repack only (K staged in-place by attn from kv + qa)
  pack_vt_k<<<1024, 256, 0, stream>>>(kv, Vt);

  // attention -> att   (512 blocks x 512 threads, layered-balanced, XCD-local)
  attn_k<<<512, 512, 0, stream>>>(qout, kv, qa, Vt, att);

  // out = att @ o_w
  transpose_cast_k<<<dim3(2048 / 32, 2048 / 32), 256, 0, stream>>>(o_w, wt, 2048, 2048);
  gemm_bt<0><<<(2048 / 128) * (4096 / 128), 256, 0, stream>>>(att, wt, out, 4096, 2048, 2048);
}

// Round 8
// 366.047 us; speedup vs baseline: 1.1234x; 1.1234x over previous
//
#include <hip/hip_runtime.h>
#include <cstdint>
#include <cstddef>

typedef unsigned short u16;
typedef short short8 __attribute__((ext_vector_type(8)));
typedef float f32x4 __attribute__((ext_vector_type(4)));

#define B_   2
#define T_   2048
#define H_   16
#define HID_ 2048
#define DQK_ 192
#define DV_  128
#define AW_  3072   // fused a-proj output width (q_a 1536 | kv_raw 1536)

__device__ __forceinline__ float bf2f(u16 u) {
  unsigned int v = ((unsigned int)u) << 16;
  return __builtin_bit_cast(float, v);
}
__device__ __forceinline__ u16 f2bf(float f) {
  unsigned int u = __builtin_bit_cast(unsigned int, f);
  u += 0x7fff + ((u >> 16) & 1);   // round-to-nearest-even
  return (u16)(u >> 16);
}
__device__ __forceinline__ void load_lds16(const void* g, void* l) {
  __builtin_amdgcn_global_load_lds((const __attribute__((address_space(1))) void*)g,
                                   (__attribute__((address_space(3))) void*)l, 16, 0, 0);
}

// ---------------- cast f32 -> bf16 (8 elems/thread) ----------------
__global__ __launch_bounds__(256) void cast_f32_bf16(const float* __restrict__ x,
                                                     u16* __restrict__ y) {
  size_t i = ((size_t)blockIdx.x * 256 + threadIdx.x) * 8;
  float4 a = *(const float4*)&x[i];
  float4 b = *(const float4*)&x[i + 4];
  u16 r[8];
  r[0] = f2bf(a.x); r[1] = f2bf(a.y); r[2] = f2bf(a.z); r[3] = f2bf(a.w);
  r[4] = f2bf(b.x); r[5] = f2bf(b.y); r[6] = f2bf(b.z); r[7] = f2bf(b.w);
  *(uint4*)&y[i] = *(const uint4*)&r[0];
}

// ---------------- W (K x N) f32  ->  Wt (N x K) bf16 ----------------
__global__ __launch_bounds__(256) void transpose_cast_k(const float* __restrict__ W,
                                                        u16* __restrict__ Wt,
                                                        int K, int N) {
  __shared__ u16 tile[32][33];
  int n0 = blockIdx.x * 32, k0 = blockIdx.y * 32;
  int tx = threadIdx.x & 31, ty = threadIdx.x >> 5;
#pragma unroll
  for (int i = 0; i < 32; i += 8)
    tile[ty + i][tx] = f2bf(W[(size_t)(k0 + ty + i) * N + n0 + tx]);
  __syncthreads();
#pragma unroll
  for (int i = 0; i < 32; i += 8)
    Wt[(size_t)(n0 + ty + i) * K + k0 + tx] = tile[tx][ty + i];
}

// ---------------- RMSNorm over rows (bf16 in/out, f32 weight) ----------------
__global__ __launch_bounds__(256) void rmsnorm_k(const u16* __restrict__ in, int in_stride,
                                                 int L, const float* __restrict__ w,
                                                 u16* __restrict__ out, int out_stride) {
  int row = blockIdx.x;
  const u16* x = in + (size_t)row * in_stride;
  float ss = 0.f;
  for (int i = threadIdx.x * 8; i < L; i += 2048) {
    uint4 v = *(const uint4*)&x[i];
    const u16* p = (const u16*)&v;
#pragma unroll
    for (int e = 0; e < 8; ++e) { float f = bf2f(p[e]); ss += f * f; }
  }
#pragma unroll
  for (int m = 32; m >= 1; m >>= 1) ss += __shfl_xor(ss, m);
  __shared__ float red[4];
  if ((threadIdx.x & 63) == 0) red[threadIdx.x >> 6] = ss;
  __syncthreads();
  ss = red[0] + red[1] + red[2] + red[3];
  float inv = rsqrtf(ss / (float)L + 1e-6f);
  u16* o = out + (size_t)row * out_stride;
  for (int i = threadIdx.x * 8; i < L; i += 2048) {
    uint4 v = *(const uint4*)&x[i];
    const u16* p = (const u16*)&v;
    u16 r8[8];
#pragma unroll
    for (int e = 0; e < 8; ++e) r8[e] = f2bf(bf2f(p[e]) * inv * w[i + e]);
    *(uint4*)&o[i] = *(const uint4*)&r8[0];
  }
}

// ---------------- GEMM: A(MxK) bf16 row-major, Bt(NxK) bf16, C(MxN) ----------------
// 128x128 tile, BK=32, 4 waves (2x2), 64x64 per wave.
// NEW vs m97 structure: (a) 3-buffer depth-2 prefetch with COUNTED vmcnt (T3+T4):
// stage K-tile t+2 while computing t; boundary waits vmcnt(4) (t+1 guaranteed
// landed, t+2's 4 loads stay in flight) -- never drains to 0 in the main loop.
// (b) T2-equivalent XOR swizzle via rule #21: LDS linear for global_load_lds,
// global SOURCE col pre-XORed (slot ^= (row>>1)&3), reads use the same XOR ->
// ds_read_b128 hits 2 lanes/16B-slot = conflict-free (2-way is free, m136).
// LDS 3x(8+8)KB = 48KB -> 3 blocks/CU (12 waves/CU).
// EPI: 0 = f32 row-major, 1 = bf16 row-major, 3 = bf16 * softmax scale
template <int EPI>
__global__ __launch_bounds__(256) void gemm_bt(const u16* __restrict__ A,
                                               const u16* __restrict__ Bt,
                                               void* __restrict__ Cout,
                                               int M, int N, int K) {
  __shared__ u16 As[3][128 * 32];
  __shared__ u16 Bs[3][128 * 32];
  const int nbx = N >> 7;
  const int bx = blockIdx.x % nbx, by = blockIdx.x / nbx;
  const int m0 = by << 7, n0 = bx << 7;
  const int tid = threadIdx.x, w = tid >> 6, lane = tid & 63;
  const int wr = w >> 1, wc = w & 1;
  const int llo = lane & 15, lhi = lane >> 4;
  f32x4 acc[4][4] = {};

  // staging: 512 chunks (128 rows x 4 slots of 16B) per matrix; 2 chunks/thread.
  // source col pre-swizzled (rule #21): slot s of row r holds col (s ^ ((r>>1)&3)).
  const int c0 = tid, c1 = tid + 256;
  const int ar0 = c0 >> 2, s0_ = c0 & 3;
  const int ar1 = c1 >> 2, s1_ = c1 & 3;
  const u16* Asrc0 = A + (size_t)(m0 + ar0) * K + (s0_ ^ ((ar0 >> 1) & 3)) * 8;
  const u16* Asrc1 = A + (size_t)(m0 + ar1) * K + (s1_ ^ ((ar1 >> 1) & 3)) * 8;
  const u16* Bsrc0 = Bt + (size_t)(n0 + ar0) * K + (s0_ ^ ((ar0 >> 1) & 3)) * 8;
  const u16* Bsrc1 = Bt + (size_t)(n0 + ar1) * K + (s1_ ^ ((ar1 >> 1) & 3)) * 8;

  // fragment read offsets (u16 units), swizzled chunk = lhi ^ ((row>>1)&3)
  int aoff[4], boff[4];
#pragma unroll
  for (int i = 0; i < 4; ++i) {
    int rowa = wr * 64 + i * 16 + llo;
    aoff[i] = (rowa * 4 + (lhi ^ ((rowa >> 1) & 3))) * 8;
    int rowb = wc * 64 + i * 16 + llo;
    boff[i] = (rowb * 4 + (lhi ^ ((rowb >> 1) & 3))) * 8;
  }

#define STAGE_KT(kt, buf)                                   \
  do {                                                      \
    int k0_ = (kt) << 5;                                    \
    load_lds16(Asrc0 + k0_, &As[(buf)][c0 * 8]);            \
    load_lds16(Asrc1 + k0_, &As[(buf)][c1 * 8]);            \
    load_lds16(Bsrc0 + k0_, &Bs[(buf)][c0 * 8]);            \
    load_lds16(Bsrc1 + k0_, &Bs[(buf)][c1 * 8]);            \
  } while (0)

  const int NT = K >> 5;
  STAGE_KT(0, 0);
  STAGE_KT(1, 1);
  asm volatile("s_waitcnt vmcnt(4)" ::: "memory");   // tile 0 landed; tile 1 in flight
  __builtin_amdgcn_s_barrier();

  int cur = 0, nxt = 2;
  for (int kt = 0; kt < NT; ++kt) {
    if (kt + 2 < NT) STAGE_KT(kt + 2, nxt);
    short8 af[4], bfr[4];
#pragma unroll
    for (int i = 0; i < 4; ++i) af[i] = *(const short8*)&As[cur][aoff[i]];
#pragma unroll
    for (int j = 0; j < 4; ++j) bfr[j] = *(const short8*)&Bs[cur][boff[j]];
    __builtin_amdgcn_s_setprio(1);
#pragma unroll
    for (int i = 0; i < 4; ++i)
#pragma unroll
      for (int j = 0; j < 4; ++j)
        acc[i][j] = __builtin_amdgcn_mfma_f32_16x16x32_bf16(af[i], bfr[j], acc[i][j], 0, 0, 0);
    __builtin_amdgcn_s_setprio(0);
    if (kt + 2 < NT) asm volatile("s_waitcnt vmcnt(4)" ::: "memory");  // t+1 landed
    else             asm volatile("s_waitcnt vmcnt(0)" ::: "memory");  // tail drain
    __builtin_amdgcn_s_barrier();
    cur = (cur == 2) ? 0 : cur + 1;
    nxt = (nxt == 2) ? 0 : nxt + 1;
  }
#undef STAGE_KT

  if constexpr (EPI == 0) {
    float* C = (float*)Cout;
#pragma unroll
    for (int i = 0; i < 4; ++i)
#pragma unroll
      for (int j = 0; j < 4; ++j)
#pragma unroll
        for (int r = 0; r < 4; ++r)
          C[(size_t)(m0 + wr * 64 + i * 16 + lhi * 4 + r) * N + (n0 + wc * 64 + j * 16 + llo)] =
              acc[i][j][r];
  } else {
    const float scale = (EPI == 3) ? 0.10412163f : 1.0f;  // log2(e)/sqrt(192)
    u16* C = (u16*)Cout;
#pragma unroll
    for (int i = 0; i < 4; ++i)
#pragma unroll
      for (int j = 0; j < 4; ++j)
#pragma unroll
        for (int r = 0; r < 4; ++r)
          C[(size_t)(m0 + wr * 64 + i * 16 + lhi * 4 + r) * N + (n0 + wc * 64 + j * 16 + llo)] =
              f2bf(acc[i][j][r] * scale);
  }
}

// ---------------- V repack: kv cols 128..255 per head -> Vt (B,H,128,T) ----------------
__global__ __launch_bounds__(256) void pack_vt_k(const u16* __restrict__ kv, u16* __restrict__ Vt) {
  __shared__ u16 tile[64][136];
  const int nt = T_ / 64;  // 32
  int t0 = (blockIdx.x % nt) * 64;
  int bh = blockIdx.x / nt;
  int b = bh >> 4, h = bh & 15;
  int row = threadIdx.x >> 4;     // 0..15
  int ck = threadIdx.x & 15;      // 16 chunks of 8 = 128 dims
#pragma unroll
  for (int i = 0; i < 64; i += 16) {
    uint4 v = *(const uint4*)&kv[((size_t)(b * T_) + t0 + row + i) * 4096 + h * 256 + 128 + ck * 8];
    *(uint4*)&tile[row + i][ck * 8] = v;
  }
  __syncthreads();
  int d = threadIdx.x >> 1;
  int th = (threadIdx.x & 1) * 32;
  u16 tmp[32];
#pragma unroll
  for (int e = 0; e < 32; ++e) tmp[e] = tile[th + e][d];
#pragma unroll
  for (int e = 0; e < 32; e += 8)
    *(uint4*)&Vt[((size_t)bh * 128 + d) * T_ + t0 + th + e] = *(const uint4*)&tmp[e];
}

// ---------------- causal flash attention (round-6 verified version) ----------------
// grid = 32 bh x 16 pairs; block 256 (4 waves x 16 q-rows); k-tile 64.
// Each block runs TWO 64-row Q-tiles (qt=31-pr then qt=pr) -> 33 k-tiles/block.
// global_load_lds staging, K double-buffered, counted vmcnt; source-side XOR
// swizzle (rule #21); exp2 softmax w/ prefolded scale; defer-max THR=8;
// deferred l-reduce. LDS 72KB -> 2 blocks/CU. 127us verified in round 6.
__global__ __launch_bounds__(256, 2) void attn_k(const u16* __restrict__ q,
                                                 const u16* __restrict__ kv,
                                                 const u16* __restrict__ kvraw,
                                                 const u16* __restrict__ Vt,
                                                 u16* __restrict__ att) {
  constexpr int KLD = 192, VLD = 64, PLD = 64;
  __shared__ u16 Ks[2][64 * KLD];
  __shared__ u16 Vs[128 * VLD];
  __shared__ u16 Ps[64 * PLD];
  const int idx = (int)blockIdx.x;
  const int bh = idx >> 4, pr = idx & 15;
  const int b = bh >> 4, h = bh & 15;
  const int bT = b * T_;
  const int tid = threadIdx.x, w = tid >> 6, lane = tid & 63;
  const int llo = lane & 15, lhi = lane >> 4;
  const u16* Vb = Vt + (size_t)bh * DV_ * T_;

  // per-thread K staging sources, swizzle pre-folded into source (rule #21)
  const u16* kbase[6]; int kstr[6];
#pragma unroll
  for (int ii = 0; ii < 6; ++ii) {
    int c = ii * 256 + tid;            // 1536 chunks = 64 rows x 24 chunks
    int rr = c / 24, chk = c - rr * 24;
    int sc = chk ^ (rr & 7);           // source chunk for linear LDS slot
    if (sc < 16) { kbase[ii] = kv + (size_t)(bT + rr) * 4096 + h * 256 + sc * 8; kstr[ii] = 4096; }
    else { kbase[ii] = kvraw + (size_t)(bT + rr) * AW_ + 2048 + h * 64 + (sc - 16) * 8; kstr[ii] = AW_; }
  }
  int voff[4];
#pragma unroll
  for (int ii = 0; ii < 4; ++ii) {
    int c = ii * 256 + tid;            // 1024 chunks = 128 d-rows x 8 chunks
    int rr = c >> 3, chk = c & 7;
    voff[ii] = rr * T_ + (chk ^ (rr & 7)) * 8;
  }

#pragma unroll
  for (int pass = 0; pass < 2; ++pass) {
    const int qt = pass == 0 ? 31 - pr : pr;
    const int q0 = qt * 64;
    const int rbase = q0 + w * 16;
    short8 qf[6];
#pragma unroll
    for (int kk = 0; kk < 6; ++kk)
      qf[kk] = *(const short8*)&q[(size_t)(bT + rbase + llo) * AW_ + h * DQK_ + kk * 32 + lhi * 8];
    f32x4 oacc[8] = {};
    float m_r[4], l_r[4];
#pragma unroll
    for (int r = 0; r < 4; ++r) { m_r[r] = -1e30f; l_r[r] = 0.f; }

    // prologue: stage K[0] into Ks[0]
#pragma unroll
    for (int ii = 0; ii < 6; ++ii)
      load_lds16(kbase[ii], &Ks[0][(ii * 256 + tid) * 8]);
    asm volatile("s_waitcnt vmcnt(0)" ::: "memory");
    __builtin_amdgcn_s_barrier();
    __builtin_amdgcn_sched_barrier(0);

    const int nkt = qt + 1;
    int cur = 0;
    for (int kt = 0; kt < nkt; ++kt) {
      const int k0 = kt * 64;
      const bool hasNext = (kt + 1 < nkt);
      // issue V[kt] -> Vs
#pragma unroll
      for (int ii = 0; ii < 4; ++ii)
        load_lds16(Vb + k0 + voff[ii], &Vs[(ii * 256 + tid) * 8]);
      // issue K[kt+1] -> other buffer
      if (hasNext) {
        u16* kd = Ks[cur ^ 1];
#pragma unroll
        for (int ii = 0; ii < 6; ++ii)
          load_lds16(kbase[ii] + (size_t)(k0 + 64) * kstr[ii], &kd[(ii * 256 + tid) * 8]);
      }
      // S = Q K^T from Ks[cur]
      const u16* kbuf = Ks[cur];
      f32x4 s[4] = {};
      __builtin_amdgcn_s_setprio(1);
#pragma unroll
      for (int kk = 0; kk < 6; ++kk) {
        const int col = kk * 32 + lhi * 8;
        short8 kf[4];
#pragma unroll
        for (int j = 0; j < 4; ++j) {
          const int row = j * 16 + llo;
          kf[j] = *(const short8*)&kbuf[row * KLD + (col ^ ((row & 7) << 3))];
        }
#pragma unroll
        for (int j = 0; j < 4; ++j)
          s[j] = __builtin_amdgcn_mfma_f32_16x16x32_bf16(qf[kk], kf[j], s[j], 0, 0, 0);
      }
      __builtin_amdgcn_s_setprio(0);
      // online softmax (exp2 domain; Q pre-scaled by log2e/sqrt(192))
      const bool needMask = (k0 + 63 > rbase);
#pragma unroll
      for (int r = 0; r < 4; ++r) {
        const int qrow = rbase + lhi * 4 + r;
        float sv[4];
#pragma unroll
        for (int j = 0; j < 4; ++j) {
          float x = s[j][r];
          if (needMask) { int kcol = k0 + j * 16 + llo; x = (kcol <= qrow) ? x : -1e30f; }
          sv[j] = x;
        }
        float mx = fmaxf(fmaxf(sv[0], sv[1]), fmaxf(sv[2], sv[3]));
#pragma unroll
        for (int mk = 1; mk < 16; mk <<= 1) mx = fmaxf(mx, __shfl_xor(mx, mk));
        if (!__all(mx - m_r[r] <= 8.f)) {   // defer-max (T13)
          float mnew = fmaxf(m_r[r], mx);
          float alpha = exp2f(m_r[r] - mnew);
          m_r[r] = mnew;
          l_r[r] *= alpha;
#pragma unroll
          for (int jo = 0; jo < 8; ++jo) oacc[jo][r] *= alpha;
        }
        float rs = 0.f;
        const int prow = w * 16 + lhi * 4 + r;
#pragma unroll
        for (int j = 0; j < 4; ++j) {
          float p = exp2f(sv[j] - m_r[r]);
          rs += p;
          int pcol = j * 16 + llo;
          Ps[prow * PLD + (pcol ^ ((prow & 7) << 3))] = f2bf(p);
        }
        l_r[r] += rs;   // per-lane partial; cross-lane reduce in epilogue
      }
      // V staged? (counted: leave the 6 K loads in flight)
      if (hasNext) asm volatile("s_waitcnt vmcnt(6)" ::: "memory");
      else         asm volatile("s_waitcnt vmcnt(0)" ::: "memory");
      __builtin_amdgcn_s_barrier();
      __builtin_amdgcn_sched_barrier(0);
      // PV (wave-local P rows; same-wave LDS RAW ordered by lgkmcnt)
      __builtin_amdgcn_s_setprio(1);
#pragma unroll
      for (int kk2 = 0; kk2 < 2; ++kk2) {
        const int prow = w * 16 + llo;
        const int pcol = kk2 * 32 + lhi * 8;
        short8 pf = *(const short8*)&Ps[prow * PLD + (pcol ^ ((prow & 7) << 3))];
#pragma unroll
        for (int jo = 0; jo < 8; ++jo) {
          const int vrow = jo * 16 + llo;
          short8 vf = *(const short8*)&Vs[vrow * VLD + (pcol ^ ((vrow & 7) << 3))];
          oacc[jo] = __builtin_amdgcn_mfma_f32_16x16x32_bf16(pf, vf, oacc[jo], 0, 0, 0);
        }
      }
      __builtin_amdgcn_s_setprio(0);
      // end of tile: K[t+1] landed; all waves done with Vs & Ks[cur]
      asm volatile("s_waitcnt vmcnt(0)" ::: "memory");
      __builtin_amdgcn_s_barrier();
      __builtin_amdgcn_sched_barrier(0);
      cur ^= 1;
    }
    // epilogue: reduce l partials across 16-lane group, store
#pragma unroll
    for (int r = 0; r < 4; ++r) {
      float lr = l_r[r];
#pragma unroll
      for (int mk = 1; mk < 16; mk <<= 1) lr += __shfl_xor(lr, mk);
      const int qrow = rbase + lhi * 4 + r;
      const float linv = 1.f / lr;
#pragma unroll
      for (int jo = 0; jo < 8; ++jo)
        att[((size_t)bT + qrow) * (H_ * DV_) + h * DV_ + jo * 16 + llo] =
            f2bf(oacc[jo][r] * linv);
    }
  }
}

// ---------------- launch ----------------
extern "C" void kernel_launch(void* const* d_in, const int* in_sizes, int n_in,
                              void* d_out, int out_size, void* d_ws, size_t ws_size,
                              hipStream_t stream) {
  const float* hs      = (const float*)d_in[0];
  const float* q_a_w   = (const float*)d_in[1];
  const float* q_a_ln  = (const float*)d_in[2];
  const float* q_b_w   = (const float*)d_in[3];
  const float* kv_a_w  = (const float*)d_in[4];
  const float* kv_a_ln = (const float*)d_in[5];
  const float* kv_b_w  = (const float*)d_in[6];
  const float* o_w     = (const float*)d_in[7];
  float* out = (float*)d_out;
  char* ws = (char*)d_ws;

  u16* hid  = (u16*)(ws + 0);          // 16.78 MB  (B*T, 2048) bf16
  u16* wt   = (u16*)(ws + 16777216);   // 12.58 MB  transposed weight (reused)
  u16* qa   = (u16*)(ws + 29360128);   // 25.17 MB  fused a-out: [q_a 1536 | kv_raw 1536]
  u16* qan  = (u16*)(ws + 54525952);   // 12.58 MB  q_a normed / later kv_latent
  u16* qout = (u16*)(ws + 67108864);   // 25.17 MB  q (B*T, 16*192), pre-scaled
  u16* att  = (u16*)(ws + 92274688);   // 16.78 MB  attn out (B*T, 2048)
  u16* kv   = (u16*)(ws + 109051904);  // 33.55 MB  kv_b out (k_nope|v per head)
  u16* Vt   = (u16*)(ws + 142606336);  // 16.78 MB  (B,H,128,T)

  cast_f32_bf16<<<4096, 256, 0, stream>>>(hs, hid);

  // fused a-proj: [q_a | kv_raw] = hid @ [q_a_w | kv_a_w]
  transpose_cast_k<<<dim3(1536 / 32, 2048 / 32), 256, 0, stream>>>(q_a_w, wt, 2048, 1536);
  transpose_cast_k<<<dim3(1536 / 32, 2048 / 32), 256, 0, stream>>>(kv_a_w, wt + (size_t)1536 * 2048, 2048, 1536);
  gemm_bt<1><<<(3072 / 128) * (4096 / 128), 256, 0, stream>>>(hid, wt, qa, 4096, 3072, 2048);

  // rmsnorm q_a -> qan
  rmsnorm_k<<<4096, 256, 0, stream>>>(qa, AW_, 1536, q_a_ln, qan, 1536);

  // q = qan @ q_b_w  (bf16, pre-scaled by log2e/sqrt(192))
  transpose_cast_k<<<dim3(3072 / 32, 1536 / 32), 256, 0, stream>>>(q_b_w, wt, 1536, 3072);
  gemm_bt<3><<<(3072 / 128) * (4096 / 128), 256, 0, stream>>>(qan, wt, qout, 4096, 3072, 1536);

  // rmsnorm kv latent (kv_raw = qa cols 1536..3071) -> qan (stride 512)
  rmsnorm_k<<<4096, 256, 0, stream>>>(qa + 1536, AW_, 512, kv_a_ln, qan, 512);

  // kv = kv_latent @ kv_b_w
  transpose_cast_k<<<dim3(4096 / 32, 512 / 32), 256, 0, stream>>>(kv_b_w, wt, 512, 4096);
  gemm_bt<1><<<(4096 / 128) * (4096 / 128), 256, 0, stream>>>(qan, wt, kv, 4096, 4096, 512);

  // V repack only (K staged in-place by attn from kv + qa)
  pack_vt_k<<<1024, 256, 0, stream>>>(kv, Vt);

  // attention -> att   (512 balanced blocks, round-6 verified kernel)
  attn_k<<<512, 256, 0, stream>>>(qout, kv, qa, Vt, att);

  // out = att @ o_w
  transpose_cast_k<<<dim3(2048 / 32, 2048 / 32), 256, 0, stream>>>(o_w, wt, 2048, 2048);
  gemm_bt<0><<<(2048 / 128) * (4096 / 128), 256, 0, stream>>>(att, wt, out, 4096, 2048, 2048);
}